// Round 8
// baseline (99.086 us; speedup 1.0000x reference)
//
#include <hip/hip_runtime.h>

// SpikeEncoder, single fused kernel + tiny reduce.
// Block (by,bx): gemm1 slab (fused gather + fp16 hi/lo split, 2-term MFMA)
// -> ct in LDS (fp32, two s-half passes, bit-identical to R7) -> LIF counts
// in registers -> in-block gemm2 partial vs W2 column-slab -> part[bx].
// reduce_out: out = (sum_bx part + 640*b2)/64.
//
// ws: part[4][64][1024] f32 = 1 MB

#define TSTEPS 10
#define SEQ    64
#define BATCH  64
#define EDIM   1024
#define HDIM   1024

typedef unsigned short u16;
typedef __attribute__((ext_vector_type(8))) _Float16 half8;
typedef __attribute__((ext_vector_type(8))) unsigned short ushort8;
typedef __attribute__((ext_vector_type(4))) float  f32x4;

union h16 { _Float16 f; u16 u; };
static __device__ __forceinline__ u16 f2h_bits(float x) { h16 t; t.f = (_Float16)x; return t.u; }
static __device__ __forceinline__ float h2f(u16 b)      { h16 t; t.u = b; return (float)t.f; }

#define BM 64
#define BN 256
#define BK 32
#define NT (EDIM / BK)
// u16 offsets inside one 24KB staging buffer:
#define AHo 0         // [64][32]
#define ALo 2048
#define WHo 4096      // [256][32]
#define BUFU 12288    // 24KB in u16 units
#define CT_STRIDE 35  // odd stride: LIF column reads are 2-way bank-aliased (free)

__global__ __launch_bounds__(256, 1) void spike_mega(
    const int* __restrict__ idx,
    const float* __restrict__ emb,
    const float* __restrict__ W1,
    const float* __restrict__ bias1,
    const float* __restrict__ W2,
    const float* __restrict__ pthr, const float* __restrict__ pleak,
    float* __restrict__ part)
{
    __shared__ unsigned char smem[49152];   // 2x24KB staging; later ct[256][35] f32
    __shared__ int ridx[64];
    __shared__ float cntL[256];
    u16*   stage = (u16*)smem;
    float* ct    = (float*)smem;            // 35840 B < 49152

    const int bid = blockIdx.x;             // 256 blocks = 1/CU
    const int bx  = bid & 3;                // k-slab: same-bx blocks share W1/W2 slabs in L2
    const int by  = bid >> 2;               // batch element
    const int col0 = bx * BN;

    const int tid  = threadIdx.x;
    const int wave = tid >> 6, lane = tid & 63;
    const int wn   = wave;                  // wave grid 1x4, tile 64x64
    const int lrow = lane & 15, kgrp = lane >> 4;

    if (tid < 64) ridx[tid] = idx[tid * 64 + by];   // GEMM row s = word s of batch by
    __syncthreads();

    // reg-staging assignments
    const int ar  = tid >> 2;                 // A row 0..63
    const int aq  = tid & 3;                  // 8-float chunk
    const int asl = aq ^ ((ar >> 1) & 3);     // swizzled slot
    const int wr  = tid;                      // W row 0..255
    const int wsw = (wr >> 1) & 3;
    const float* wbase = W1 + (size_t)(col0 + wr) * EDIM;

    float4 a0, a1, w[8];
    auto LOADR = [&](int k0) {
        const float* ap = emb + (size_t)ridx[ar] * EDIM + k0 + aq * 8;
        a0 = *(const float4*)ap;
        a1 = *(const float4*)(ap + 4);
        const float* wp = wbase + k0;
#pragma unroll
        for (int q = 0; q < 8; ++q) w[q] = *(const float4*)(wp + q * 4);
    };

    auto CVTWRITE = [&](int b) {
        u16* lb = stage + b * BUFU;
        float xa[8] = {a0.x, a0.y, a0.z, a0.w, a1.x, a1.y, a1.z, a1.w};
        ushort8 h, l;
#pragma unroll
        for (int j = 0; j < 8; ++j) {
            u16 hh = f2h_bits(xa[j]);
            h[j] = hh;
            l[j] = f2h_bits((xa[j] - h2f(hh)) * 2048.0f);
        }
        *(ushort8*)(lb + AHo + ar * 32 + asl * 8) = h;
        *(ushort8*)(lb + ALo + ar * 32 + asl * 8) = l;
#pragma unroll
        for (int q = 0; q < 4; ++q) {
            ushort8 p;
            const float4 wa = w[q * 2], wb = w[q * 2 + 1];
            p[0] = f2h_bits(wa.x); p[1] = f2h_bits(wa.y);
            p[2] = f2h_bits(wa.z); p[3] = f2h_bits(wa.w);
            p[4] = f2h_bits(wb.x); p[5] = f2h_bits(wb.y);
            p[6] = f2h_bits(wb.z); p[7] = f2h_bits(wb.w);
            *(ushort8*)(lb + WHo + wr * 32 + (q ^ wsw) * 8) = p;
        }
    };

    f32x4 acc[4][4], acl[4][4];
    const f32x4 zero = {0.f, 0.f, 0.f, 0.f};
#pragma unroll
    for (int m = 0; m < 4; ++m)
#pragma unroll
        for (int n = 0; n < 4; ++n) { acc[m][n] = zero; acl[m][n] = zero; }

    auto COMPUTE = [&](int b) {
        const u16* lb = stage + b * BUFU;
        half8 ah[4], al[4], bh[4];
#pragma unroll
        for (int n = 0; n < 4; ++n) {
            const int c = wn * 64 + n * 16 + lrow;
            const int s = kgrp ^ ((c >> 1) & 3);
            bh[n] = *(const half8*)(lb + WHo + c * 32 + s * 8);
        }
#pragma unroll
        for (int m = 0; m < 4; ++m) {
            const int r = m * 16 + lrow;
            const int s = kgrp ^ ((r >> 1) & 3);
            const u16* p = lb + AHo + r * 32 + s * 8;
            ah[m] = *(const half8*)p;
            al[m] = *(const half8*)(p + (ALo - AHo));
        }
#pragma unroll
        for (int m = 0; m < 4; ++m)
#pragma unroll
            for (int n = 0; n < 4; ++n) {
                acc[m][n] = __builtin_amdgcn_mfma_f32_16x16x32_f16(ah[m], bh[n], acc[m][n], 0, 0, 0);
                acl[m][n] = __builtin_amdgcn_mfma_f32_16x16x32_f16(al[m], bh[n], acl[m][n], 0, 0, 0);
            }
    };

    // T14 2-phase k-loop (R6/R7 structure; proven equal to deeper pipelines here)
    LOADR(0);
#pragma unroll 2
    for (int t = 0; t < NT; ++t) {
        CVTWRITE(t & 1);
        __syncthreads();
        if (t + 1 < NT) LOADR((t + 1) * BK);
        COMPUTE(t & 1);
        __syncthreads();
    }

    // ---- epilogue + LIF, two s-half passes (ct fp32, bit-identical math) ----
    const float thr = pthr[0];
    const float lk  = pleak[0];
    const float b1v = bias1[col0 + tid];
    float mem1 = 0.f, c = 0.f;

#pragma unroll
    for (int p = 0; p < 2; ++p) {
        __syncthreads();   // pass 0: after k-loop; pass 1: LIF reads of pass 0 done
        // C/D layout: col=lane&15, row=(lane>>4)*4+j. ct[kcol][s_local], s = p*32+s_local
#pragma unroll
        for (int n = 0; n < 4; ++n) {
            const int kc = wn * 64 + n * 16 + lrow;
#pragma unroll
            for (int ml = 0; ml < 2; ++ml) {
                const int m  = p * 2 + ml;
                const int sb = ml * 16 + kgrp * 4;
#pragma unroll
                for (int j = 0; j < 4; ++j)
                    ct[kc * CT_STRIDE + sb + j] =
                        acc[m][n][j] + acl[m][n][j] * (1.0f / 2048.0f);
            }
        }
        __syncthreads();
        const float* row = ct + tid * CT_STRIDE;
        for (int sl = 0; sl < 32; ++sl) {
            const float x = row[sl] + b1v;
#pragma unroll
            for (int t = 0; t < TSTEPS; ++t) {
                mem1 = lk * mem1 + x;
                if (mem1 > thr) { c += 1.f; mem1 -= thr; }
            }
        }
    }

    cntL[tid] = c;
    __syncthreads();

    // ---- in-block gemm2 partial: part[bx][by][h] = sum_j cntL[j]*W2[h][col0+j]
#pragma unroll
    for (int q = 0; q < 4; ++q) {
        const int h = q * 256 + tid;
        const float4* wrp = (const float4*)(W2 + (size_t)h * HDIM + col0);
        float s = 0.f;
#pragma unroll 8
        for (int i = 0; i < 64; ++i) {
            const float4 ww = wrp[i];     // per-thread row stream, L2-resident slab
            s += cntL[4 * i] * ww.x + cntL[4 * i + 1] * ww.y +
                 cntL[4 * i + 2] * ww.z + cntL[4 * i + 3] * ww.w;  // LDS broadcasts
        }
        part[((size_t)bx * BATCH + by) * HDIM + h] = s;
    }
}

// ---- out = (sum_bx part + 640*b2) / 64 ------------------------------------
__global__ __launch_bounds__(256) void reduce_out(
    const float* __restrict__ part,
    const float* __restrict__ b2,
    float* __restrict__ out)
{
    const int i = blockIdx.x * 256 + threadIdx.x;
    const float s = part[i] + part[65536 + i] + part[131072 + i] + part[196608 + i];
    out[i] = (s + (float)(SEQ * TSTEPS) * b2[i & (HDIM - 1)]) * (1.0f / (float)BATCH);
}

extern "C" void kernel_launch(void* const* d_in, const int* in_sizes, int n_in,
                              void* d_out, int out_size, void* d_ws, size_t ws_size,
                              hipStream_t stream)
{
    (void)in_sizes; (void)n_in; (void)out_size; (void)ws_size;

    const int*   idx  = (const int*)d_in[0];
    const float* emb  = (const float*)d_in[1];
    const float* W1   = (const float*)d_in[2];
    const float* b1   = (const float*)d_in[3];
    const float* W2   = (const float*)d_in[4];
    const float* b2   = (const float*)d_in[5];
    const float* thr  = (const float*)d_in[6];
    const float* leak = (const float*)d_in[7];
    float* out  = (float*)d_out;
    float* part = (float*)d_ws;   // 1 MB

    spike_mega<<<dim3(BATCH * (HDIM / BN)), 256, 0, stream>>>(
        idx, emb, W1, b1, W2, thr, leak, part);

    reduce_out<<<dim3((BATCH * HDIM) / 256), 256, 0, stream>>>(part, b2, out);
}

// Round 9
// 55.059 us; speedup vs baseline: 1.7996x; 1.7996x over previous
//
#include <hip/hip_runtime.h>

// SpikeEncoder: out[b,h] = ( sum_k count[b,k]*W2[h,k] + S*T*b2[h] ) / B
// GEMM1 in split-fp16 MFMA, 2 terms: A*W ~= Ahi*Whi + 2^-11*(Alo')*Whi.
// Rows permuted to r' = b*64 + s; LIF recurrence fused in-block.
// R9: R4 structure + 3-buffer staging (48KB LDS) + launch_bounds(256,3)
// -> 3 blocks/CU (12 waves) vs R4's 2; depth-2 counted-vmcnt retained.
// R8's profile showed the kernel is LATENCY-bound (MfmaUtil 5%, VALU 15%,
// HBM 4%, 1 blk/CU) -> occupancy is the matching lever.
//
// ws: part[4MB) | cnt[256KB) | Ahi(8M) Alo(8M) Whi(2M)

#define TSTEPS 10
#define SEQ    64
#define BATCH  64
#define EDIM   1024
#define HDIM   1024
#define NROW   (SEQ * BATCH)   // 4096
#define KSPLIT 16

typedef unsigned short u16;
typedef __attribute__((ext_vector_type(8))) _Float16 half8;
typedef __attribute__((ext_vector_type(8))) unsigned short ushort8;
typedef __attribute__((ext_vector_type(4))) float  f32x4;

union h16 { _Float16 f; u16 u; };

__device__ __forceinline__ u16 f2h_bits(float x) {
    h16 t; t.f = (_Float16)x; return t.u;       // RNE
}
__device__ __forceinline__ float h2f(u16 b) {
    h16 t; t.u = b; return (float)t.f;
}
__device__ __forceinline__ void gld16(const u16* g, u16* l) {
    __builtin_amdgcn_global_load_lds(
        (const __attribute__((address_space(1))) void*)g,
        (__attribute__((address_space(3))) void*)l, 16, 0, 0);
}

// ---- split fp32 -> fp16 hi + scaled-lo. rows [0,4096): emb gather with the
// ---- b*64+s permutation; rows [4096,5120): W1 (hi only).
__global__ __launch_bounds__(256) void split_pack(
    const float* __restrict__ emb, const float* __restrict__ W1,
    const int* __restrict__ idx,
    u16* __restrict__ ahi, u16* __restrict__ alo, u16* __restrict__ whi)
{
    const int t = blockIdx.x * 256 + threadIdx.x;
    const int r = t >> 7;
    const int c = (t & 127) << 3;
    if (r < NROW) {
        const int srow = idx[(r & 63) * 64 + (r >> 6)];   // r = b*64+s
        const float* src = emb + (size_t)srow * EDIM + c;
        float4 v0 = *(const float4*)src;
        float4 v1 = *(const float4*)(src + 4);
        float x[8] = {v0.x, v0.y, v0.z, v0.w, v1.x, v1.y, v1.z, v1.w};
        ushort8 h, l;
#pragma unroll
        for (int j = 0; j < 8; ++j) {
            u16 hh = f2h_bits(x[j]);
            h[j] = hh;
            l[j] = f2h_bits((x[j] - h2f(hh)) * 2048.0f);
        }
        *(ushort8*)(ahi + (size_t)r * EDIM + c) = h;
        *(ushort8*)(alo + (size_t)r * EDIM + c) = l;
    } else {
        const int rw = r - NROW;
        const float* src = W1 + (size_t)rw * EDIM + c;
        float4 v0 = *(const float4*)src;
        float4 v1 = *(const float4*)(src + 4);
        float x[8] = {v0.x, v0.y, v0.z, v0.w, v1.x, v1.y, v1.z, v1.w};
        ushort8 h;
#pragma unroll
        for (int j = 0; j < 8; ++j) h[j] = f2h_bits(x[j]);
        *(ushort8*)(whi + (size_t)rw * EDIM + c) = h;
    }
}

// ---- GEMM1(split-fp16 MFMA, 2-term) + in-block LIF spike count -----------
#define BM 64
#define BN 128
#define BK 32
#define NT (EDIM / BK)
// u16 offsets inside one 16KB buffer:
#define AH 0          // [64][32]
#define AL 2048
#define WH 4096       // [128][32]
#define BUF 8192      // 16KB in u16 units

__global__ __launch_bounds__(256, 3) void gemm1_lif(
    const u16* __restrict__ Ahi, const u16* __restrict__ Alo,
    const u16* __restrict__ Whi,
    const float* __restrict__ bias1,
    const float* __restrict__ pthr, const float* __restrict__ pleak,
    float* __restrict__ cnt)
{
    __shared__ float smf[12288];                // 48KB: 3x16KB staging / ct alias
    u16*   stage = (u16*)smf;
    float* ct    = smf;                         // [128][66] fp32 (33792B)

    // bijective XCD-chunk swizzle: 512 blocks, 8 by x 8 bx chunk per XCD
    const int bid = blockIdx.x;
    const int loc = bid >> 3;
    const int by  = (bid & 7) * 8 + (loc & 7);  // 0..63  (= batch b)
    const int bx  = loc >> 3;                   // 0..7   (k-slab)
    const int row0 = by * BM, col0 = bx * BN;

    const int tid  = threadIdx.x;
    const int wave = tid >> 6, lane = tid & 63;
    const int wn   = wave;                      // wave grid 1x4, tile 64x32
    const int lrow = lane & 15, kgrp = lane >> 4;

    // staging source: 16 rows per gld16, inverse slot-swizzled k-chunk
    const int srr = lane >> 2;                                // 0..15
    const int kcs = (((lane & 3) ^ ((lane >> 3) & 3)) << 3);  // u16 offset
    const size_t aoff = (size_t)(row0 + wave * 16 + srr) * EDIM + kcs;
    const size_t w0   = (size_t)(col0 + wave * 32 + srr) * EDIM + kcs;
    const size_t w1   = w0 + (size_t)16 * EDIM;

    f32x4 acc[4][2], acl[4][2];
    const f32x4 zero = {0.f, 0.f, 0.f, 0.f};
#pragma unroll
    for (int m = 0; m < 4; ++m)
#pragma unroll
        for (int n = 0; n < 2; ++n) { acc[m][n] = zero; acl[m][n] = zero; }

    // per-thread gld16 count per STAGE = 4 (vmcnt accounting)
    auto STAGE = [&](int k0, int b) {
        u16* lb = stage + b * BUF;
        gld16(Ahi + aoff + k0, lb + AH + wave * 512);
        gld16(Alo + aoff + k0, lb + AL + wave * 512);
        gld16(Whi + w0 + k0, lb + WH + wave * 1024);
        gld16(Whi + w1 + k0, lb + WH + wave * 1024 + 512);
    };

    auto COMPUTE = [&](int b) {
        const u16* lb = stage + b * BUF;
        half8 ah[4], al[4], bh[2];
#pragma unroll
        for (int n = 0; n < 2; ++n) {
            const int c = wn * 32 + n * 16 + lrow;
            const int s = kgrp ^ ((c >> 1) & 3);
            bh[n] = *(const half8*)(lb + WH + c * 32 + s * 8);
        }
#pragma unroll
        for (int m = 0; m < 4; ++m) {
            const int r = m * 16 + lrow;
            const int s = kgrp ^ ((r >> 1) & 3);
            const u16* p = lb + AH + r * 32 + s * 8;
            ah[m] = *(const half8*)p;
            al[m] = *(const half8*)(p + (AL - AH));
        }
#pragma unroll
        for (int m = 0; m < 4; ++m)
#pragma unroll
            for (int n = 0; n < 2; ++n) {
                acc[m][n] = __builtin_amdgcn_mfma_f32_16x16x32_f16(ah[m], bh[n], acc[m][n], 0, 0, 0);
                acl[m][n] = __builtin_amdgcn_mfma_f32_16x16x32_f16(al[m], bh[n], acl[m][n], 0, 0, 0);
            }
    };

    // ---- depth-2 pipeline, 3 buffers, counted vmcnt, 2 barriers/step.
    // Race ledger: STAGE(t+2) overwrites buf[(t+2)%3] = buf[(t-1)%3], whose
    // readers (COMPUTE(t-1)) finished before the post-COMPUTE barrier of
    // step t-1 -> safe. vmcnt(8): outstanding = STAGE(t+1)+STAGE(t+2).
    STAGE(0, 0);
    STAGE(BK, 1);
    int cc = 0, cs = 2;
    for (int t = 0; t < NT - 2; ++t) {
        STAGE((t + 2) * BK, cs);
        asm volatile("s_waitcnt vmcnt(8)" ::: "memory");
        __builtin_amdgcn_s_barrier();
        __builtin_amdgcn_sched_barrier(0);
        COMPUTE(cc);
        __builtin_amdgcn_s_barrier();
        cc = (cc == 2) ? 0 : cc + 1;
        cs = (cs == 2) ? 0 : cs + 1;
    }
    // t = NT-2: only tile NT-1 outstanding
    asm volatile("s_waitcnt vmcnt(4)" ::: "memory");
    __builtin_amdgcn_s_barrier();
    __builtin_amdgcn_sched_barrier(0);
    COMPUTE(cc);
    cc = (cc == 2) ? 0 : cc + 1;
    // t = NT-1: drain
    asm volatile("s_waitcnt vmcnt(0)" ::: "memory");
    __builtin_amdgcn_s_barrier();
    __builtin_amdgcn_sched_barrier(0);
    COMPUTE(cc);
    __syncthreads();   // all LDS reads done -> safe to alias with ct

    // C/D layout: col=lane&15, row=(lane>>4)*4+j.  ct[kcol][s], stride 66.
#pragma unroll
    for (int n = 0; n < 2; ++n) {
        const int kc = wn * 32 + n * 16 + lrow;
#pragma unroll
        for (int m = 0; m < 4; ++m) {
            const int sb = m * 16 + kgrp * 4;
#pragma unroll
            for (int j = 0; j < 4; ++j)
                ct[kc * 66 + sb + j] = acc[m][n][j] + acl[m][n][j] * (1.0f / 2048.0f);
        }
    }
    __syncthreads();

    // LIF recurrence: thread k walks ct[k][s], s=0..63, 10 substeps each
    if (tid < BN) {
        const float thr = pthr[0];
        const float lk  = pleak[0];
        const float b1v = bias1[col0 + tid];
        const float* row = ct + tid * 66;
        float mem1 = 0.f, c = 0.f;
        for (int s = 0; s < SEQ; ++s) {
            const float x = row[s] + b1v;
#pragma unroll
            for (int t = 0; t < TSTEPS; ++t) {
                mem1 = lk * mem1 + x;
                if (mem1 > thr) { c += 1.f; mem1 -= thr; }
            }
        }
        cnt[(size_t)by * HDIM + col0 + tid] = c;
    }
}

// ---- GEMM2 (K-split partials): part[kc][b][h] ----------------------------
__global__ __launch_bounds__(256) void gemm2_partial(
    const float* __restrict__ cnt,
    const float* __restrict__ W2,
    float* __restrict__ part)
{
    __shared__ float As[32][68];
    __shared__ float Bs[32][132];

    const int tid   = threadIdx.x;
    const int col0  = blockIdx.x * 128;
    const int kc    = blockIdx.y;
    const int kbase = kc * 64;

    const int lr = tid >> 3;
    const int lc = (tid & 7) * 4;
    const int tm = (tid >> 4) * 4;
    const int tn = (tid & 15) * 4;

    float acc[4][8];
#pragma unroll
    for (int i = 0; i < 4; ++i)
#pragma unroll
        for (int j = 0; j < 8; ++j) acc[i][j] = 0.f;

    for (int kt = 0; kt < 2; ++kt) {
        const int k0 = kbase + kt * 32;
#pragma unroll
        for (int p = 0; p < 2; ++p) {
            int r = p * 32 + lr;
            float4 v = *(const float4*)(cnt + (size_t)r * HDIM + k0 + lc);
            As[lc + 0][r] = v.x; As[lc + 1][r] = v.y;
            As[lc + 2][r] = v.z; As[lc + 3][r] = v.w;
        }
#pragma unroll
        for (int p = 0; p < 4; ++p) {
            int r = p * 32 + lr;
            float4 v = *(const float4*)(W2 + (size_t)(col0 + r) * HDIM + k0 + lc);
            Bs[lc + 0][r] = v.x; Bs[lc + 1][r] = v.y;
            Bs[lc + 2][r] = v.z; Bs[lc + 3][r] = v.w;
        }
        __syncthreads();
#pragma unroll 8
        for (int k = 0; k < 32; ++k) {
            float4 a   = *(const float4*)&As[k][tm];
            float4 bb0 = *(const float4*)&Bs[k][tn];
            float4 bb1 = *(const float4*)&Bs[k][tn + 64];
            float av[4] = {a.x, a.y, a.z, a.w};
            float bv[8] = {bb0.x, bb0.y, bb0.z, bb0.w, bb1.x, bb1.y, bb1.z, bb1.w};
#pragma unroll
            for (int i = 0; i < 4; ++i)
#pragma unroll
                for (int j = 0; j < 8; ++j)
                    acc[i][j] += av[i] * bv[j];
        }
        __syncthreads();
    }

#pragma unroll
    for (int i = 0; i < 4; ++i) {
        float* prow = part + (size_t)kc * (BATCH * HDIM) + (size_t)(tm + i) * HDIM + col0;
        float4 o0, o1;
        o0.x = acc[i][0]; o0.y = acc[i][1]; o0.z = acc[i][2]; o0.w = acc[i][3];
        o1.x = acc[i][4]; o1.y = acc[i][5]; o1.z = acc[i][6]; o1.w = acc[i][7];
        *(float4*)(prow + tn)      = o0;
        *(float4*)(prow + tn + 64) = o1;
    }
}

// ---- final reduce: out = (sum_kc part + 640*b2) / 64 ----------------------
__global__ __launch_bounds__(256) void reduce_out(
    const float* __restrict__ part,
    const float* __restrict__ b2,
    float* __restrict__ out)
{
    const int i = blockIdx.x * 256 + threadIdx.x;
    float s = 0.f;
#pragma unroll
    for (int kc = 0; kc < KSPLIT; ++kc)
        s += part[(size_t)kc * (BATCH * HDIM) + i];
    const int h = i & (HDIM - 1);
    out[i] = (s + (float)(SEQ * TSTEPS) * b2[h]) * (1.0f / (float)BATCH);
}

extern "C" void kernel_launch(void* const* d_in, const int* in_sizes, int n_in,
                              void* d_out, int out_size, void* d_ws, size_t ws_size,
                              hipStream_t stream)
{
    (void)in_sizes; (void)n_in; (void)out_size; (void)ws_size;

    const int*   idx  = (const int*)d_in[0];
    const float* emb  = (const float*)d_in[1];
    const float* W1   = (const float*)d_in[2];
    const float* b1   = (const float*)d_in[3];
    const float* W2   = (const float*)d_in[4];
    const float* b2   = (const float*)d_in[5];
    const float* thr  = (const float*)d_in[6];
    const float* leak = (const float*)d_in[7];
    float* out = (float*)d_out;

    char* ws = (char*)d_ws;
    float* part = (float*)ws;                                       // 4 MB
    float* cnt  = (float*)(ws + (size_t)KSPLIT * BATCH * HDIM * 4); // 256 KB
    u16* ahi = (u16*)(ws + (size_t)KSPLIT * BATCH * HDIM * 4 + (size_t)BATCH * HDIM * 4);
    u16* alo = ahi + (size_t)NROW * EDIM;
    u16* whi = alo + (size_t)NROW * EDIM;

    split_pack<<<dim3((NROW + HDIM) * 128 / 256), 256, 0, stream>>>(
        emb, W1, idx, ahi, alo, whi);

    gemm1_lif<<<dim3((NROW / BM) * (HDIM / BN)), 256, 0, stream>>>(
        ahi, alo, whi, b1, thr, leak, cnt);

    gemm2_partial<<<dim3(HDIM / 128, KSPLIT), 256, 0, stream>>>(cnt, W2, part);

    reduce_out<<<dim3((BATCH * HDIM) / 256), 256, 0, stream>>>(part, b2, out);
}